// Round 6
// baseline (270.471 us; speedup 1.0000x reference)
//
#include <hip/hip_runtime.h>
#include <math.h>

// SSM_18597208391915: HiPPO-LegT recurrence, O(N) semiseparable solve.
// Ad = (I-cA)^{-1}(I+cA) = 2M - I  =>  h' = tanh(2*M(h + c*u*P) - h).
// R16: transcendental surgery + compiler-scheduled DPP.
//   (1) Pade [7/6] tanh replaces the exp2/sigmoid tail. Work in PLAIN
//       y-space: state m = h (upc loses the 2*log2e factor; ivd/ka/cB/
//       triangle constants never had it). y clamped to +-4.8 (v_med3);
//       tanh(y) ~ y*N(t)/D(t), t=y^2, N=((t+378)t+17325)t+135135,
//       D=((28t+3150)t+62370)t+135135. Max err 1.5e-5 (|y|<4), 7e-5
//       (saturation). Shared quad-rcp kept (den products < 2e26, safe).
//       Kills 4 exp2 + 4 fmin per step (~68 issue-cy).
//   (2) No inline asm: scan expressed as fmaf(Alev, dpp(B), B) builtins
//       so the compiler fuses v_fmac_f32_dpp and fills DPP hazard slots
//       with real work (R15's split-asm s_nops burned ~14 cy/step).
//   (3) Exclusive shift = ONE wave_shr:1 DPP (crosses row boundary
//       natively) + cndmask zeroing lane 32 (batch boundary).
// Structure from R14/R15 (verified): 2 batches/block in lane halves,
// NW=8, EPL=4, composed-stream publish, 16-step register inner loop,
// one barrier per chunk.

#define SEQ     784
#define OUT_DIM 10
#define NW      8
#define CH      16            // steps per chunk
#define NCH     (SEQ/CH)      // 49
#define EPL     4             // elems per lane per batch: 8*32*4 = 1024

typedef float v2f __attribute__((ext_vector_type(2)));

#if __has_builtin(__builtin_elementwise_fma)
__device__ __forceinline__ v2f fma2(v2f a, v2f b, v2f c) {
    return __builtin_elementwise_fma(a, b, c);
}
#else
__device__ __forceinline__ v2f fma2(v2f a, v2f b, v2f c) {
    v2f r; r.x = fmaf(a.x, b.x, c.x); r.y = fmaf(a.y, b.y, c.y); return r;
}
#endif

// DPP move with explicit old: masked/invalid lanes get `old`.
template<int CTRL, int ROW_MASK>
__device__ __forceinline__ float dpp_mov(float src, float old) {
    return __int_as_float(__builtin_amdgcn_update_dpp(
        __float_as_int(old), __float_as_int(src), CTRL, ROW_MASK, 0xf, false));
}
// DPP move, bound_ctrl: invalid lanes read 0.
template<int CTRL>
__device__ __forceinline__ float dpp_bc0(float src) {
    return __int_as_float(__builtin_amdgcn_update_dpp(
        0, __float_as_int(src), CTRL, 0xf, 0xf, true));
}
// ctrls: row_shr:N = 0x110|N, row_bcast15 = 0x142, wave_shr:1 = 0x138

__global__ __launch_bounds__(512, 2)
void ssm_hippo_scan(const float* __restrict__ x,     // (512, 784)
                    const float* __restrict__ C,     // (1024)
                    const float* __restrict__ W,     // (10)
                    const float* __restrict__ bvec,  // (10)
                    float* __restrict__ out)         // (512, 10)
{
    const int b0   = blockIdx.x * 2;   // this block's two batch elems
    const int tid  = threadIdx.x;
    const int wv   = tid >> 6;         // wave: hidden slice [wv*128, +128)
    const int lane = tid & 63;
    const int lh   = lane & 31;        // lane within half
    const int h    = lane >> 5;        // 0 = batch b0, 1 = batch b0+1

    __shared__ __align__(16) float u_s[2][SEQ];
    __shared__ __align__(16) float tot_s[NW-1][2][SEQ]; // composed B-streams
    __shared__ double part_s[NW][2];

    for (int t = tid; t < SEQ; t += 512) {
        u_s[0][t] = x[(b0 + 0) * SEQ + t];
        u_s[1][t] = x[(b0 + 1) * SEQ + t];
    }

    const double hdt = 0.5 / (double)SEQ;             // c = dt/2

    // ---- per-element constants (n = wv*128 + lh*4 + i) - SAME for both
    // halves (depend on lane&31 only). fp64-derived. PLAIN y-space:
    //   w_n = v_n = h_n + c p_n u ;  S_{n+1} = alpha_n S_n + pdin_n w_n
    //   y_n = ivd_n w_n - h_n - hp_n S_n ;  h_n' = tanh(y_n)
    v2f upc01, upc23, ivd01, ivd23, cB01, cB23;
    v2f ka01, ka23, c20_30, c21_31;
    float t10, t32;
    float Alev0, Alev1, Alev2, Alev3, Alev4, Aexcl;
    float PhiW;
    {
        double p[EPL], d[EPL], a[EPL], pdin[EPL], hp[EPL];
#pragma unroll
        for (int i = 0; i < EPL; ++i) {
            const int n = wv * 128 + lh * EPL + i;
            p[i]    = sqrt(1.0 + 2.0 * (double)n);
            d[i]    = 1.0 + hdt * (double)(n + 1);
            a[i]    = 1.0 - hdt * p[i] * p[i] / d[i];
            pdin[i] = p[i] / d[i];
            hp[i]   = 2.0 * hdt * p[i] / d[i];
        }
        upc01 = (v2f){(float)(hdt * p[0]), (float)(hdt * p[1])};
        upc23 = (v2f){(float)(hdt * p[2]), (float)(hdt * p[3])};
        ivd01 = (v2f){(float)(2.0 / d[0]), (float)(2.0 / d[1])};
        ivd23 = (v2f){(float)(2.0 / d[2]), (float)(2.0 / d[3])};
        ka01  = (v2f){(float)(-hp[0]), (float)(-hp[1] * a[0])};
        ka23  = (v2f){(float)(-hp[2] * a[0]*a[1]),
                      (float)(-hp[3] * a[0]*a[1]*a[2])};
        cB01  = (v2f){(float)(a[1]*a[2]*a[3] * pdin[0]),
                      (float)(a[2]*a[3] * pdin[1])};
        cB23  = (v2f){(float)(a[3] * pdin[2]), (float)(pdin[3])};
        t10   = (float)(-hp[1] * pdin[0]);
        c20_30= (v2f){(float)(-hp[2] * a[1] * pdin[0]),
                      (float)(-hp[3] * a[2] * a[1] * pdin[0])};
        c21_31= (v2f){(float)(-hp[2] * pdin[1]),
                      (float)(-hp[3] * a[2] * pdin[1])};
        t32   = (float)(-hp[3] * pdin[2]);

        // 32-lane scan level constants (5 levels; never cross lane 32)
        float A = (float)(a[0]*a[1]*a[2]*a[3]);   // per-lane decay
        Alev0 = A; A *= dpp_mov<0x111, 0xf>(A, 1.0f);  // row_shr:1
        Alev1 = A; A *= dpp_mov<0x112, 0xf>(A, 1.0f);  // row_shr:2
        Alev2 = A; A *= dpp_mov<0x114, 0xf>(A, 1.0f);  // row_shr:4
        Alev3 = A; A *= dpp_mov<0x118, 0xf>(A, 1.0f);  // row_shr:8
        Alev4 = A; A *= dpp_mov<0x142, 0xa>(A, 1.0f);  // bcast15 rows 1,3
        // A = 32-lane inclusive alpha-product per half
        const float Ae_raw = dpp_mov<0x111, 0xf>(A, 1.0f); // shift, old=1
        const float Ae_fix = dpp_mov<0x142, 0xa>(A, 1.0f); // lane15/47 val
        Aexcl = (lh == 16) ? Ae_fix : Ae_raw;  // exclusive alpha-product

        // own wave's total decay Phi over its 128 elems (closed form)
        double np = 1.0, dp = 1.0;
        for (int n = wv * 128; n < wv * 128 + 128; ++n) {
            np *= 1.0 - hdt * (double)n;
            dp *= 1.0 + hdt * (double)(n + 1);
        }
        PhiW = (float)(np / dp);
    }

    const bool not32 = (lane != 32);   // batch-boundary zero for wave_shr
    // Pade [7/6] tanh coefficients (pk pairs)
    const v2f CN2 = (v2f){  378.0f,   378.0f};
    const v2f CN1 = (v2f){17325.0f, 17325.0f};
    const v2f CC0 = (v2f){135135.0f, 135135.0f};
    const v2f CD3 = (v2f){   28.0f,    28.0f};
    const v2f CD2 = (v2f){ 3150.0f,  3150.0f};
    const v2f CD1 = (v2f){62370.0f, 62370.0f};
    const float YC = 4.8f;

    __syncthreads();                   // u_s ready

    // ---- state: m = h   (init 0)
    v2f m01 = (v2f){0.0f, 0.0f}, m23 = (v2f){0.0f, 0.0f};

#pragma unroll 1
    for (int tick = 0; tick < NCH + NW - 1; ++tick) {
        const int ch = tick - wv;      // this wave's chunk index
        if (0 <= ch && ch < NCH) {
            // ---- bulk register loads: u's and the one incoming stream
            float4 u4[CH/4];
            float  Tin[CH];
            {
                const float4* up = (const float4*)&u_s[h][ch * CH];
#pragma unroll
                for (int q = 0; q < CH/4; ++q) u4[q] = up[q];
            }
            if (wv == 0) {
#pragma unroll
                for (int k = 0; k < CH; ++k) Tin[k] = 0.0f;
            } else {
                const float4* bp = (const float4*)&tot_s[wv - 1][h][ch * CH];
#pragma unroll
                for (int q = 0; q < CH/4; ++q) {
                    const float4 v0 = bp[q];
                    Tin[4*q+0] = v0.x; Tin[4*q+1] = v0.y;
                    Tin[4*q+2] = v0.z; Tin[4*q+3] = v0.w;
                }
            }
            float Bacc[CH];

#pragma unroll
            for (int k = 0; k < CH; ++k) {
                const float u = ((const float*)&u4[k>>2])[k&3];
                const v2f  uu = (v2f){u, u};

                // ---- head: w_i = upc_i*u + m_i   (pk)
                const v2f w01 = fma2(upc01, uu, m01);
                const v2f w23 = fma2(upc23, uu, m23);

                // ---- tanh-arg bases (pk, -m via neg modifier)
                const v2f bb01 = fma2(ivd01, w01, -m01);
                const v2f bb23 = fma2(ivd23, w23, -m23);

                // triangle (w-only part of y1..y3)
                const float g1t = fmaf(t10, w01.x, bb01.y);
                const v2f w0s = (v2f){w01.x, w01.x};
                const v2f w1s = (v2f){w01.y, w01.y};
                v2f tri23 = fma2(c21_31, w1s,
                                 (v2f){bb23.x, fmaf(t32, w23.x, bb23.y)});
                tri23 = fma2(c20_30, w0s, tri23);

                // ---- lane-inclusive affine-B (pk dot + h-add)
                const v2f bt = fma2(cB23, w23, cB01 * w01);
                float B = bt.x + bt.y;

                // ---- 32-lane affine scan (builtin DPP; compiler fuses
                // v_fmac_f32_dpp and fills hazard slots with the pk ops)
                B = fmaf(Alev0, dpp_bc0<0x111>(B), B);
                B = fmaf(Alev1, dpp_bc0<0x112>(B), B);
                B = fmaf(Alev2, dpp_bc0<0x114>(B), B);
                B = fmaf(Alev3, dpp_bc0<0x118>(B), B);
                B = fmaf(Alev4, dpp_mov<0x142, 0xa>(B, 0.0f), B);
                Bacc[k] = B;                        // publish later

                // exclusive prefix: wave_shr:1 crosses rows natively;
                // lane 0 -> 0 (bound_ctrl), lane 32 -> 0 (batch boundary)
                const float Tst_raw = dpp_bc0<0x138>(B);
                const float Tst     = not32 ? Tst_raw : 0.0f;
                const float Tent    = fmaf(Aexcl, Tin[k], Tst);
                const v2f  TentV    = (v2f){Tent, Tent};

                // ---- per-element tanh args (pk)
                const v2f gb01 = (v2f){bb01.x, g1t};
                const v2f y01  = fma2(ka01, TentV, gb01);
                const v2f y23  = fma2(ka23, TentV, tri23);

                // ---- Pade [7/6] tanh, clamp +-4.8, ONE shared rcp
                v2f x01, x23;
                x01.x = __builtin_amdgcn_fmed3f(y01.x, -YC, YC);
                x01.y = __builtin_amdgcn_fmed3f(y01.y, -YC, YC);
                x23.x = __builtin_amdgcn_fmed3f(y23.x, -YC, YC);
                x23.y = __builtin_amdgcn_fmed3f(y23.y, -YC, YC);
                const v2f t01 = x01 * x01, t23 = x23 * x23;
                // N = ((t+378)t+17325)t+135135 ; num = x*N
                const v2f n01 = fma2(fma2(t01 + CN2, t01, CN1), t01, CC0);
                const v2f n23 = fma2(fma2(t23 + CN2, t23, CN1), t23, CC0);
                const v2f num01 = x01 * n01;
                const v2f num23 = x23 * n23;
                // D = ((28t+3150)t+62370)t+135135
                const v2f d01 = fma2(fma2(fma2(CD3, t01, CD2), t01, CD1),
                                     t01, CC0);
                const v2f d23 = fma2(fma2(fma2(CD3, t23, CD2), t23, CD1),
                                     t23, CC0);
                const float p01 = d01.x * d01.y;
                const float p23 = d23.x * d23.y;
                const float ip  = __builtin_amdgcn_rcpf(p01 * p23);
                const float i01 = p23 * ip;          // 1/(d0*d1)
                const float i23 = p01 * ip;          // 1/(d2*d3)
                // m_i' = num_i * d_other / (d_i*d_other)
                const v2f nd01 = num01 * __builtin_shufflevector(d01, d01, 1, 0);
                const v2f nd23 = num23 * __builtin_shufflevector(d23, d23, 1, 0);
                m01 = nd01 * (v2f){i01, i01};
                m23 = nd23 * (v2f){i23, i23};
            }

            // publish composed running totals from BOTH half-ends:
            // lane 31 (batch h=0) and lane 63 (batch h=1)
            if (wv < NW - 1 && lh == 31) {
                float4* tp = (float4*)&tot_s[wv][h][ch * CH];
#pragma unroll
                for (int q = 0; q < CH/4; ++q)
                    tp[q] = make_float4(
                        fmaf(PhiW, Tin[4*q+0], Bacc[4*q+0]),
                        fmaf(PhiW, Tin[4*q+1], Bacc[4*q+1]),
                        fmaf(PhiW, Tin[4*q+2], Bacc[4*q+2]),
                        fmaf(PhiW, Tin[4*q+3], Bacc[4*q+3]));
            }
        }
        __syncthreads();   // one barrier per CHUNK (16 steps)
    }

    // ---- epilogue: per-half dot(h, C) over this wave's 128 elems
    double acc = 0.0;
    {
        const int base = wv * 128 + lh * EPL;
        acc = fma((double)C[base + 0], (double)m01.x, acc);
        acc = fma((double)C[base + 1], (double)m01.y, acc);
        acc = fma((double)C[base + 2], (double)m23.x, acc);
        acc = fma((double)C[base + 3], (double)m23.y, acc);
    }
#pragma unroll
    for (int off = 16; off > 0; off >>= 1)
        acc += __shfl_down(acc, off, 32);     // within 32-lane halves
    if (lh == 0) part_s[wv][h] = acc;
    __syncthreads();
    if (tid < 2 * OUT_DIM) {
        const int q = tid / OUT_DIM, j = tid - q * OUT_DIM;
        double tot = 0.0;
#pragma unroll
        for (int wq = 0; wq < NW; ++wq) tot += part_s[wq][q];
        out[(b0 + q) * OUT_DIM + j] =
            (float)fma(tot, (double)W[j], (double)bvec[j]);
    }
}

extern "C" void kernel_launch(void* const* d_in, const int* in_sizes, int n_in,
                              void* d_out, int out_size, void* d_ws, size_t ws_size,
                              hipStream_t stream) {
    const float* x  = (const float*)d_in[0];   // (512, 784, 1)
    const float* C  = (const float*)d_in[1];   // (1, 1024)
    const float* W  = (const float*)d_in[2];   // (1, 10)
    const float* bv = (const float*)d_in[3];   // (10,)
    float* out      = (float*)d_out;           // (512, 10)
    hipLaunchKernelGGL(ssm_hippo_scan, dim3(256), dim3(512), 0, stream,
                       x, C, W, bv, out);
}

// Round 7
// 222.689 us; speedup vs baseline: 1.2146x; 1.2146x over previous
//
#include <hip/hip_runtime.h>
#include <math.h>

// SSM_18597208391915: HiPPO-LegT recurrence, O(N) semiseparable solve.
// Ad = (I-cA)^{-1}(I+cA) = 2M - I  =>  h' = tanh(2*M(h + c*u*P) - h).
// R17: R15 base (205us, verified) + trans-pipe-aware tail.
// R16 post-mortem: Pade tanh (+22 VALU ops, -4 exp2) LOST 17% -> gfx950
// v_exp/v_rcp are cheap issue-wise (trans unit overlaps VALU). So invert
// the R11 shared-rcp "optimization":
//   (1) direct per-elem rcp: m_i = fma(n2c2, rcp(1+exp2(g_i)), c2).
//       Drops p01/p23/ip/tt/s chain (-6 VALU, shorter serial tail, 4
//       independent trans chains that pipeline).
//   (2) NO clamp: fmin(g,30) only protected the shared product. Direct:
//       g large -> e=inf -> q=inf -> rcp=0 -> m=c2 = correct saturation.
//   (3) wave_shr:1 exclusive shift (R16-validated): 1 DPP + lane-32
//       cndmask replaces row_shr + bcast15-fix pair.
// Structure from R14/R15 (verified): 2 batches/block in lane halves,
// NW=8, EPL=4, composed-stream publish, asm single-DPP scan blocks with
// pk fillers between, 16-step register inner loop, one barrier/chunk.

#define SEQ     784
#define OUT_DIM 10
#define NW      8
#define CH      16            // steps per chunk
#define NCH     (SEQ/CH)      // 49
#define EPL     4             // elems per lane per batch: 8*32*4 = 1024

typedef float v2f __attribute__((ext_vector_type(2)));

#if __has_builtin(__builtin_elementwise_fma)
__device__ __forceinline__ v2f fma2(v2f a, v2f b, v2f c) {
    return __builtin_elementwise_fma(a, b, c);
}
#else
__device__ __forceinline__ v2f fma2(v2f a, v2f b, v2f c) {
    v2f r; r.x = fmaf(a.x, b.x, c.x); r.y = fmaf(a.y, b.y, c.y); return r;
}
#endif

#if __has_builtin(__builtin_amdgcn_exp2f)
#define EXP2F(x) __builtin_amdgcn_exp2f(x)
#else
#define EXP2F(x) __expf(0.69314718055994531f * (x))
#endif

// DPP move with explicit old: masked/invalid lanes get `old`. (setup only)
template<int CTRL, int ROW_MASK>
__device__ __forceinline__ float dpp_mov(float src, float old) {
    return __int_as_float(__builtin_amdgcn_update_dpp(
        __float_as_int(old), __float_as_int(src), CTRL, ROW_MASK, 0xf, false));
}
// ctrls: row_shr:N = 0x110|N, row_bcast15 = 0x142, wave_shr:1 = 0x138

__global__ __launch_bounds__(512, 2)
void ssm_hippo_scan(const float* __restrict__ x,     // (512, 784)
                    const float* __restrict__ C,     // (1024)
                    const float* __restrict__ W,     // (10)
                    const float* __restrict__ bvec,  // (10)
                    float* __restrict__ out)         // (512, 10)
{
    const int b0   = blockIdx.x * 2;   // this block's two batch elems
    const int tid  = threadIdx.x;
    const int wv   = tid >> 6;         // wave: hidden slice [wv*128, +128)
    const int lane = tid & 63;
    const int lh   = lane & 31;        // lane within half
    const int h    = lane >> 5;        // 0 = batch b0, 1 = batch b0+1

    __shared__ __align__(16) float u_s[2][SEQ];
    __shared__ __align__(16) float tot_s[NW-1][2][SEQ]; // composed B-streams
    __shared__ double part_s[NW][2];

    for (int t = tid; t < SEQ; t += 512) {
        u_s[0][t] = x[(b0 + 0) * SEQ + t];
        u_s[1][t] = x[(b0 + 1) * SEQ + t];
    }

    const double hdt  = 0.5 / (double)SEQ;            // c = dt/2
    const double L2E2 = 2.0 * 1.4426950408889634;     // 2*log2(e)

    // ---- per-element constants (n = wv*128 + lh*4 + i) - SAME for both
    // halves (depend on lane&31 only). fp64-derived.
    // Exponent-space recurrence (w = m + upc*u, m = c2*h):
    //   S_{n+1} = alpha_n S_n + pdin_n w_n ; g_n = ivd_n w_n - m_n - hp_n S_n
    v2f upc01, upc23, ivd01, ivd23, cB01, cB23;
    v2f ka01, ka23, c20_30, c21_31;
    float t10, t32;
    float Alev0, Alev1, Alev2, Alev3, Alev4, Aexcl;
    float PhiW, c2, n2c2;
    {
        double p[EPL], d[EPL], a[EPL], pdin[EPL], hp[EPL];
#pragma unroll
        for (int i = 0; i < EPL; ++i) {
            const int n = wv * 128 + lh * EPL + i;
            p[i]    = sqrt(1.0 + 2.0 * (double)n);
            d[i]    = 1.0 + hdt * (double)(n + 1);
            a[i]    = 1.0 - hdt * p[i] * p[i] / d[i];
            pdin[i] = p[i] / d[i];
            hp[i]   = 2.0 * hdt * p[i] / d[i];
        }
        upc01 = (v2f){(float)(L2E2 * hdt * p[0]), (float)(L2E2 * hdt * p[1])};
        upc23 = (v2f){(float)(L2E2 * hdt * p[2]), (float)(L2E2 * hdt * p[3])};
        ivd01 = (v2f){(float)(2.0 / d[0]), (float)(2.0 / d[1])};
        ivd23 = (v2f){(float)(2.0 / d[2]), (float)(2.0 / d[3])};
        ka01  = (v2f){(float)(-hp[0]), (float)(-hp[1] * a[0])};
        ka23  = (v2f){(float)(-hp[2] * a[0]*a[1]),
                      (float)(-hp[3] * a[0]*a[1]*a[2])};
        cB01  = (v2f){(float)(a[1]*a[2]*a[3] * pdin[0]),
                      (float)(a[2]*a[3] * pdin[1])};
        cB23  = (v2f){(float)(a[3] * pdin[2]), (float)(pdin[3])};
        t10   = (float)(-hp[1] * pdin[0]);
        c20_30= (v2f){(float)(-hp[2] * a[1] * pdin[0]),
                      (float)(-hp[3] * a[2] * a[1] * pdin[0])};
        c21_31= (v2f){(float)(-hp[2] * pdin[1]),
                      (float)(-hp[3] * a[2] * pdin[1])};
        t32   = (float)(-hp[3] * pdin[2]);

        // 32-lane scan level constants (5 levels; never cross lane 32)
        float A = (float)(a[0]*a[1]*a[2]*a[3]);   // per-lane decay
        Alev0 = A; A *= dpp_mov<0x111, 0xf>(A, 1.0f);  // row_shr:1
        Alev1 = A; A *= dpp_mov<0x112, 0xf>(A, 1.0f);  // row_shr:2
        Alev2 = A; A *= dpp_mov<0x114, 0xf>(A, 1.0f);  // row_shr:4
        Alev3 = A; A *= dpp_mov<0x118, 0xf>(A, 1.0f);  // row_shr:8
        Alev4 = A; A *= dpp_mov<0x142, 0xa>(A, 1.0f);  // bcast15 rows 1,3
        // A = 32-lane inclusive alpha-product per half
        const float Ae_raw = dpp_mov<0x111, 0xf>(A, 1.0f); // shift, old=1
        const float Ae_fix = dpp_mov<0x142, 0xa>(A, 1.0f); // lane15/47 val
        Aexcl = (lh == 16) ? Ae_fix : Ae_raw;  // exclusive alpha-product

        // own wave's total decay Phi over its 128 elems (closed form)
        double np = 1.0, dp = 1.0;
        for (int n = wv * 128; n < wv * 128 + 128; ++n) {
            np *= 1.0 - hdt * (double)n;
            dp *= 1.0 + hdt * (double)(n + 1);
        }
        PhiW = (float)(np / dp);

        c2   = (float)L2E2;
        n2c2 = (float)(-2.0 * L2E2);
    }

    const bool not32 = (lane != 32);   // batch-boundary zero for wave_shr

    __syncthreads();                   // u_s ready

    // ---- state: m = c2 * h   (h = 0 -> m = 0)
    v2f m01 = (v2f){0.0f, 0.0f}, m23 = (v2f){0.0f, 0.0f};

#pragma unroll 1
    for (int tick = 0; tick < NCH + NW - 1; ++tick) {
        const int ch = tick - wv;      // this wave's chunk index
        if (0 <= ch && ch < NCH) {
            // ---- bulk register loads: u's and the one incoming stream
            float4 u4[CH/4];
            float  Tin[CH];
            {
                const float4* up = (const float4*)&u_s[h][ch * CH];
#pragma unroll
                for (int q = 0; q < CH/4; ++q) u4[q] = up[q];
            }
            if (wv == 0) {
#pragma unroll
                for (int k = 0; k < CH; ++k) Tin[k] = 0.0f;
            } else {
                const float4* bp = (const float4*)&tot_s[wv - 1][h][ch * CH];
#pragma unroll
                for (int q = 0; q < CH/4; ++q) {
                    const float4 v0 = bp[q];
                    Tin[4*q+0] = v0.x; Tin[4*q+1] = v0.y;
                    Tin[4*q+2] = v0.z; Tin[4*q+3] = v0.w;
                }
            }
            float Bacc[CH];

#pragma unroll
            for (int k = 0; k < CH; ++k) {
                const float u = ((const float*)&u4[k>>2])[k&3];
                const v2f  uu = (v2f){u, u};

                // ---- head: w_i = upc_i*u + m_i   (pk)
                const v2f w01 = fma2(upc01, uu, m01);
                const v2f w23 = fma2(upc23, uu, m23);

                // ---- sigmoid bases (pk, -m via neg modifier)
                const v2f bb01 = fma2(ivd01, w01, -m01);
                const v2f bb23 = fma2(ivd23, w23, -m23);

                // scalar triangle seeds
                const float pre = fmaf(t32, w23.x, bb23.y);
                const float g1t = fmaf(t10, w01.x, bb01.y);
                const v2f w0s = (v2f){w01.x, w01.x};
                const v2f w1s = (v2f){w01.y, w01.y};

                // ---- lane-inclusive affine-B (pk dot + h-add)
                const v2f bt = fma2(cB23, w23, cB01 * w01);
                float B = bt.x + bt.y;

                // ---- 32-lane affine scan: 5 fmac_dpp as chained blocks
                // (order forced by B), packed triangle ops between them
                // fill hazard slots when scheduled there.
                asm volatile(
                    "s_nop 1\n\t"
                    "v_fmac_f32_dpp %0, %0, %1 row_shr:1 row_mask:0xf bank_mask:0xf bound_ctrl:0"
                    : "+v"(B) : "v"(Alev0));
                v2f tri23 = fma2(c21_31, w1s, (v2f){bb23.x, pre});
                asm volatile(
                    "s_nop 1\n\t"
                    "v_fmac_f32_dpp %0, %0, %1 row_shr:2 row_mask:0xf bank_mask:0xf bound_ctrl:0"
                    : "+v"(B) : "v"(Alev1));
                tri23 = fma2(c20_30, w0s, tri23);
                asm volatile(
                    "s_nop 1\n\t"
                    "v_fmac_f32_dpp %0, %0, %1 row_shr:4 row_mask:0xf bank_mask:0xf bound_ctrl:0"
                    : "+v"(B) : "v"(Alev2));
                const v2f gb01 = (v2f){bb01.x, g1t};
                asm volatile(
                    "s_nop 1\n\t"
                    "v_fmac_f32_dpp %0, %0, %1 row_shr:8 row_mask:0xf bank_mask:0xf bound_ctrl:0"
                    : "+v"(B) : "v"(Alev3));
                asm volatile(
                    "s_nop 1\n\t"
                    "v_fmac_f32_dpp %0, %0, %1 row_bcast:15 row_mask:0xa bank_mask:0xf"
                    : "+v"(B) : "v"(Alev4));
                Bacc[k] = B;                        // publish later

                // exclusive prefix: ONE wave_shr:1 (crosses rows natively);
                // lane 0 -> 0 (bound_ctrl), lane 32 -> 0 (batch boundary)
                float Tr;
                asm volatile(
                    "s_nop 1\n\t"
                    "v_mov_b32_dpp %0, %1 wave_shr:1 row_mask:0xf bank_mask:0xf bound_ctrl:0"
                    : "=v"(Tr) : "v"(B));
                const float Tst  = not32 ? Tr : 0.0f;
                const float Tent = fmaf(Aexcl, Tin[k], Tst); // lane entry S
                const v2f  TentV = (v2f){Tent, Tent};

                // ---- flattened per-element exponents (pk)
                const v2f g01 = fma2(ka01, TentV, gb01);
                const v2f g23 = fma2(ka23, TentV, tri23);

                // ---- sigmoid tail: NO clamp, direct per-elem rcp.
                // g overflow -> e=inf -> q=inf -> rcp=0 -> m=c2 (correct
                // saturation). 4 independent exp2+rcp chains pipeline on
                // the trans unit, overlapping VALU issue.
                const float r0 = __builtin_amdgcn_rcpf(EXP2F(g01.x) + 1.0f);
                const float r1 = __builtin_amdgcn_rcpf(EXP2F(g01.y) + 1.0f);
                const float r2 = __builtin_amdgcn_rcpf(EXP2F(g23.x) + 1.0f);
                const float r3 = __builtin_amdgcn_rcpf(EXP2F(g23.y) + 1.0f);
                // m_i' = c2 + n2c2 * r_i
                m01.x = fmaf(n2c2, r0, c2);
                m01.y = fmaf(n2c2, r1, c2);
                m23.x = fmaf(n2c2, r2, c2);
                m23.y = fmaf(n2c2, r3, c2);
            }

            // publish composed running totals from BOTH half-ends:
            // lane 31 (batch h=0) and lane 63 (batch h=1)
            if (wv < NW - 1 && lh == 31) {
                float4* tp = (float4*)&tot_s[wv][h][ch * CH];
#pragma unroll
                for (int q = 0; q < CH/4; ++q)
                    tp[q] = make_float4(
                        fmaf(PhiW, Tin[4*q+0], Bacc[4*q+0]),
                        fmaf(PhiW, Tin[4*q+1], Bacc[4*q+1]),
                        fmaf(PhiW, Tin[4*q+2], Bacc[4*q+2]),
                        fmaf(PhiW, Tin[4*q+3], Bacc[4*q+3]));
            }
        }
        __syncthreads();   // one barrier per CHUNK (16 steps)
    }

    // ---- epilogue: h = m/c2; per-half dot(h, C) over 128 elems
    double acc = 0.0;
    {
        const int base = wv * 128 + lh * EPL;
        acc = fma((double)C[base + 0], (double)m01.x, acc);
        acc = fma((double)C[base + 1], (double)m01.y, acc);
        acc = fma((double)C[base + 2], (double)m23.x, acc);
        acc = fma((double)C[base + 3], (double)m23.y, acc);
    }
#pragma unroll
    for (int off = 16; off > 0; off >>= 1)
        acc += __shfl_down(acc, off, 32);     // within 32-lane halves
    if (lh == 0) part_s[wv][h] = acc;
    __syncthreads();
    if (tid < 2 * OUT_DIM) {
        const int q = tid / OUT_DIM, j = tid - q * OUT_DIM;
        double tot = 0.0;
#pragma unroll
        for (int wq = 0; wq < NW; ++wq) tot += part_s[wq][q];
        tot *= 0.34657359027997264;           // 1/c2 = ln2/2, applied once
        out[(b0 + q) * OUT_DIM + j] =
            (float)fma(tot, (double)W[j], (double)bvec[j]);
    }
}

extern "C" void kernel_launch(void* const* d_in, const int* in_sizes, int n_in,
                              void* d_out, int out_size, void* d_ws, size_t ws_size,
                              hipStream_t stream) {
    const float* x  = (const float*)d_in[0];   // (512, 784, 1)
    const float* C  = (const float*)d_in[1];   // (1, 1024)
    const float* W  = (const float*)d_in[2];   // (1, 10)
    const float* bv = (const float*)d_in[3];   // (10,)
    float* out      = (float*)d_out;           // (512, 10)
    hipLaunchKernelGGL(ssm_hippo_scan, dim3(256), dim3(512), 0, stream,
                       x, C, W, bv, out);
}

// Round 8
// 221.304 us; speedup vs baseline: 1.2222x; 1.0063x over previous
//
#include <hip/hip_runtime.h>
#include <math.h>

// SSM_18597208391915: HiPPO-LegT recurrence, O(N) semiseparable solve.
// Ad = (I-cA)^{-1}(I+cA) = 2M - I  =>  h' = tanh(2*M(h + c*u*P) - h).
// R18: consolidation on R17 (186us verified). Issue model from R12/R17
// counters: ~172 issue-cy/wave-step, fixed cost ~100cy, trans ~8cy each
// -> geometry (2 batch x 32 lanes, NW=8, EPL=4, 2 waves/SIMD) is optimal;
// recoverable slack = fill/drain + s_nop overhead.
//   (1) CH=8: ticks 56->105, fill idle 12.5%->6.7% (fill runs at 1-wave/
//       SIMD speed, ~17% of wall). Barriers +49 x ~50cy = ~1%. Net +6-8%.
//   (2) fused scan asm (R14-validated pattern): 5 fmac_dpp + wave_shr in
//       ONE block with the 6 scalar g-triangle fmas as hazard fillers
//       (1 wave64 filler = 2cy = the required 2 DPP wait states; R14
//       passed with exactly this). Only the entry s_nop remains.
//   (3) tail/constants/publish identical to R17 (bit-identical numerics).

#define SEQ     784
#define OUT_DIM 10
#define NW      8
#define CH      8             // steps per chunk
#define NCH     (SEQ/CH)      // 98
#define EPL     4             // elems per lane per batch: 8*32*4 = 1024

typedef float v2f __attribute__((ext_vector_type(2)));

#if __has_builtin(__builtin_elementwise_fma)
__device__ __forceinline__ v2f fma2(v2f a, v2f b, v2f c) {
    return __builtin_elementwise_fma(a, b, c);
}
#else
__device__ __forceinline__ v2f fma2(v2f a, v2f b, v2f c) {
    v2f r; r.x = fmaf(a.x, b.x, c.x); r.y = fmaf(a.y, b.y, c.y); return r;
}
#endif

#if __has_builtin(__builtin_amdgcn_exp2f)
#define EXP2F(x) __builtin_amdgcn_exp2f(x)
#else
#define EXP2F(x) __expf(0.69314718055994531f * (x))
#endif

// DPP move with explicit old: masked/invalid lanes get `old`. (setup only)
template<int CTRL, int ROW_MASK>
__device__ __forceinline__ float dpp_mov(float src, float old) {
    return __int_as_float(__builtin_amdgcn_update_dpp(
        __float_as_int(old), __float_as_int(src), CTRL, ROW_MASK, 0xf, false));
}
// ctrls: row_shr:N = 0x110|N, row_bcast15 = 0x142, wave_shr:1 = 0x138

__global__ __launch_bounds__(512, 2)
void ssm_hippo_scan(const float* __restrict__ x,     // (512, 784)
                    const float* __restrict__ C,     // (1024)
                    const float* __restrict__ W,     // (10)
                    const float* __restrict__ bvec,  // (10)
                    float* __restrict__ out)         // (512, 10)
{
    const int b0   = blockIdx.x * 2;   // this block's two batch elems
    const int tid  = threadIdx.x;
    const int wv   = tid >> 6;         // wave: hidden slice [wv*128, +128)
    const int lane = tid & 63;
    const int lh   = lane & 31;        // lane within half
    const int h    = lane >> 5;        // 0 = batch b0, 1 = batch b0+1

    __shared__ __align__(16) float u_s[2][SEQ];
    __shared__ __align__(16) float tot_s[NW-1][2][SEQ]; // composed B-streams
    __shared__ double part_s[NW][2];

    for (int t = tid; t < SEQ; t += 512) {
        u_s[0][t] = x[(b0 + 0) * SEQ + t];
        u_s[1][t] = x[(b0 + 1) * SEQ + t];
    }

    const double hdt  = 0.5 / (double)SEQ;            // c = dt/2
    const double L2E2 = 2.0 * 1.4426950408889634;     // 2*log2(e)

    // ---- per-element constants (n = wv*128 + lh*4 + i) - SAME for both
    // halves (depend on lane&31 only). fp64-derived.
    // Exponent-space recurrence (w = m + upc*u, m = c2*h):
    //   S_{n+1} = alpha_n S_n + pdin_n w_n ; g_n = ivd_n w_n - m_n - hp_n S_n
    v2f upc01, upc23, ivd01, ivd23, cB01, cB23;
    float ka0, ka1, ka2, ka3;
    float t10, t20, t21, t30, t31, t32;
    float Alev0, Alev1, Alev2, Alev3, Alev4, Aexcl;
    float PhiW, c2, n2c2;
    {
        double p[EPL], d[EPL], a[EPL], pdin[EPL], hp[EPL];
#pragma unroll
        for (int i = 0; i < EPL; ++i) {
            const int n = wv * 128 + lh * EPL + i;
            p[i]    = sqrt(1.0 + 2.0 * (double)n);
            d[i]    = 1.0 + hdt * (double)(n + 1);
            a[i]    = 1.0 - hdt * p[i] * p[i] / d[i];
            pdin[i] = p[i] / d[i];
            hp[i]   = 2.0 * hdt * p[i] / d[i];
        }
        upc01 = (v2f){(float)(L2E2 * hdt * p[0]), (float)(L2E2 * hdt * p[1])};
        upc23 = (v2f){(float)(L2E2 * hdt * p[2]), (float)(L2E2 * hdt * p[3])};
        ivd01 = (v2f){(float)(2.0 / d[0]), (float)(2.0 / d[1])};
        ivd23 = (v2f){(float)(2.0 / d[2]), (float)(2.0 / d[3])};
        ka0   = (float)(-hp[0]);
        ka1   = (float)(-hp[1] * a[0]);
        ka2   = (float)(-hp[2] * a[0]*a[1]);
        ka3   = (float)(-hp[3] * a[0]*a[1]*a[2]);
        cB01  = (v2f){(float)(a[1]*a[2]*a[3] * pdin[0]),
                      (float)(a[2]*a[3] * pdin[1])};
        cB23  = (v2f){(float)(a[3] * pdin[2]), (float)(pdin[3])};
        t10   = (float)(-hp[1] * pdin[0]);
        t20   = (float)(-hp[2] * a[1] * pdin[0]);
        t21   = (float)(-hp[2] * pdin[1]);
        t30   = (float)(-hp[3] * a[2] * a[1] * pdin[0]);
        t31   = (float)(-hp[3] * a[2] * pdin[1]);
        t32   = (float)(-hp[3] * pdin[2]);

        // 32-lane scan level constants (5 levels; never cross lane 32)
        float A = (float)(a[0]*a[1]*a[2]*a[3]);   // per-lane decay
        Alev0 = A; A *= dpp_mov<0x111, 0xf>(A, 1.0f);  // row_shr:1
        Alev1 = A; A *= dpp_mov<0x112, 0xf>(A, 1.0f);  // row_shr:2
        Alev2 = A; A *= dpp_mov<0x114, 0xf>(A, 1.0f);  // row_shr:4
        Alev3 = A; A *= dpp_mov<0x118, 0xf>(A, 1.0f);  // row_shr:8
        Alev4 = A; A *= dpp_mov<0x142, 0xa>(A, 1.0f);  // bcast15 rows 1,3
        // A = 32-lane inclusive alpha-product per half
        const float Ae_raw = dpp_mov<0x111, 0xf>(A, 1.0f); // shift, old=1
        const float Ae_fix = dpp_mov<0x142, 0xa>(A, 1.0f); // lane15/47 val
        Aexcl = (lh == 16) ? Ae_fix : Ae_raw;  // exclusive alpha-product

        // own wave's total decay Phi over its 128 elems (closed form)
        double np = 1.0, dp = 1.0;
        for (int n = wv * 128; n < wv * 128 + 128; ++n) {
            np *= 1.0 - hdt * (double)n;
            dp *= 1.0 + hdt * (double)(n + 1);
        }
        PhiW = (float)(np / dp);

        c2   = (float)L2E2;
        n2c2 = (float)(-2.0 * L2E2);
    }

    const bool not32 = (lane != 32);   // batch-boundary zero for wave_shr

    __syncthreads();                   // u_s ready

    // ---- state: m = c2 * h   (h = 0 -> m = 0)
    v2f m01 = (v2f){0.0f, 0.0f}, m23 = (v2f){0.0f, 0.0f};

#pragma unroll 1
    for (int tick = 0; tick < NCH + NW - 1; ++tick) {
        const int ch = tick - wv;      // this wave's chunk index
        if (0 <= ch && ch < NCH) {
            // ---- bulk register loads: u's and the one incoming stream
            float4 u4[CH/4];
            float  Tin[CH];
            {
                const float4* up = (const float4*)&u_s[h][ch * CH];
#pragma unroll
                for (int q = 0; q < CH/4; ++q) u4[q] = up[q];
            }
            if (wv == 0) {
#pragma unroll
                for (int k = 0; k < CH; ++k) Tin[k] = 0.0f;
            } else {
                const float4* bp = (const float4*)&tot_s[wv - 1][h][ch * CH];
#pragma unroll
                for (int q = 0; q < CH/4; ++q) {
                    const float4 v0 = bp[q];
                    Tin[4*q+0] = v0.x; Tin[4*q+1] = v0.y;
                    Tin[4*q+2] = v0.z; Tin[4*q+3] = v0.w;
                }
            }
            float Bacc[CH];

#pragma unroll
            for (int k = 0; k < CH; ++k) {
                const float u = ((const float*)&u4[k>>2])[k&3];
                const v2f  uu = (v2f){u, u};

                // ---- head: w_i = upc_i*u + m_i   (pk)
                const v2f w01 = fma2(upc01, uu, m01);
                const v2f w23 = fma2(upc23, uu, m23);

                // ---- sigmoid bases (pk, -m via neg modifier)
                const v2f bb01 = fma2(ivd01, w01, -m01);
                const v2f bb23 = fma2(ivd23, w23, -m23);

                // ---- lane-inclusive affine-B (pk dot + h-add)
                const v2f bt = fma2(cB23, w23, cB01 * w01);
                float B = bt.x + bt.y;

                // ---- 32-lane affine scan + exclusive shift, ONE asm
                // block: 5 fmac_dpp + wave_shr mov_dpp, with the 6 scalar
                // g-triangle fmas as the DPP 2-wait-state fillers (pattern
                // HW-validated in R14). Entry guarded by s_nop (B written
                // by the pk-add just above).
                float Tr, g1t, g2t, g3t;
                asm volatile(
                    "s_nop 1\n\t"
                    "v_fmac_f32_dpp %[B], %[B], %[A0] row_shr:1 row_mask:0xf bank_mask:0xf bound_ctrl:0\n\t"
                    "v_fma_f32 %[g1], %[c10], %[w0], %[b1]\n\t"
                    "v_fmac_f32_dpp %[B], %[B], %[A1] row_shr:2 row_mask:0xf bank_mask:0xf bound_ctrl:0\n\t"
                    "v_fma_f32 %[g2], %[c21], %[w1], %[b2]\n\t"
                    "v_fmac_f32_dpp %[B], %[B], %[A2] row_shr:4 row_mask:0xf bank_mask:0xf bound_ctrl:0\n\t"
                    "v_fma_f32 %[g2], %[c20], %[w0], %[g2]\n\t"
                    "v_fmac_f32_dpp %[B], %[B], %[A3] row_shr:8 row_mask:0xf bank_mask:0xf bound_ctrl:0\n\t"
                    "v_fma_f32 %[g3], %[c32], %[w2], %[b3]\n\t"
                    "v_fmac_f32_dpp %[B], %[B], %[A4] row_bcast:15 row_mask:0xa bank_mask:0xf\n\t"
                    "v_fma_f32 %[g3], %[c31], %[w1], %[g3]\n\t"
                    "v_mov_b32_dpp %[Tr], %[B] wave_shr:1 row_mask:0xf bank_mask:0xf bound_ctrl:0\n\t"
                    "v_fma_f32 %[g3], %[c30], %[w0], %[g3]\n\t"
                    : [B]"+v"(B), [Tr]"=&v"(Tr),
                      [g1]"=&v"(g1t), [g2]"=&v"(g2t), [g3]"=&v"(g3t)
                    : [A0]"v"(Alev0), [A1]"v"(Alev1), [A2]"v"(Alev2),
                      [A3]"v"(Alev3), [A4]"v"(Alev4),
                      [c10]"v"(t10), [c20]"v"(t20), [c21]"v"(t21),
                      [c30]"v"(t30), [c31]"v"(t31), [c32]"v"(t32),
                      [w0]"v"(w01.x), [w1]"v"(w01.y), [w2]"v"(w23.x),
                      [b1]"v"(bb01.y), [b2]"v"(bb23.x), [b3]"v"(bb23.y));
                Bacc[k] = B;                        // publish later

                // exclusive prefix: lane 0 -> 0 (bound_ctrl), lane 32 -> 0
                const float Tst  = not32 ? Tr : 0.0f;
                const float Tent = fmaf(Aexcl, Tin[k], Tst); // lane entry S

                // ---- flattened per-element exponents
                const float g0 = fmaf(ka0, Tent, bb01.x);
                const float g1 = fmaf(ka1, Tent, g1t);
                const float g2 = fmaf(ka2, Tent, g2t);
                const float g3 = fmaf(ka3, Tent, g3t);

                // ---- sigmoid tail: NO clamp, direct per-elem rcp.
                // g overflow -> e=inf -> q=inf -> rcp=0 -> m=c2 (correct
                // saturation). 4 independent trans chains pipeline.
                const float r0 = __builtin_amdgcn_rcpf(EXP2F(g0) + 1.0f);
                const float r1 = __builtin_amdgcn_rcpf(EXP2F(g1) + 1.0f);
                const float r2 = __builtin_amdgcn_rcpf(EXP2F(g2) + 1.0f);
                const float r3 = __builtin_amdgcn_rcpf(EXP2F(g3) + 1.0f);
                // m_i' = c2 + n2c2 * r_i
                m01.x = fmaf(n2c2, r0, c2);
                m01.y = fmaf(n2c2, r1, c2);
                m23.x = fmaf(n2c2, r2, c2);
                m23.y = fmaf(n2c2, r3, c2);
            }

            // publish composed running totals from BOTH half-ends:
            // lane 31 (batch h=0) and lane 63 (batch h=1)
            if (wv < NW - 1 && lh == 31) {
                float4* tp = (float4*)&tot_s[wv][h][ch * CH];
#pragma unroll
                for (int q = 0; q < CH/4; ++q)
                    tp[q] = make_float4(
                        fmaf(PhiW, Tin[4*q+0], Bacc[4*q+0]),
                        fmaf(PhiW, Tin[4*q+1], Bacc[4*q+1]),
                        fmaf(PhiW, Tin[4*q+2], Bacc[4*q+2]),
                        fmaf(PhiW, Tin[4*q+3], Bacc[4*q+3]));
            }
        }
        __syncthreads();   // one barrier per CHUNK (8 steps)
    }

    // ---- epilogue: h = m/c2; per-half dot(h, C) over 128 elems
    double acc = 0.0;
    {
        const int base = wv * 128 + lh * EPL;
        acc = fma((double)C[base + 0], (double)m01.x, acc);
        acc = fma((double)C[base + 1], (double)m01.y, acc);
        acc = fma((double)C[base + 2], (double)m23.x, acc);
        acc = fma((double)C[base + 3], (double)m23.y, acc);
    }
#pragma unroll
    for (int off = 16; off > 0; off >>= 1)
        acc += __shfl_down(acc, off, 32);     // within 32-lane halves
    if (lh == 0) part_s[wv][h] = acc;
    __syncthreads();
    if (tid < 2 * OUT_DIM) {
        const int q = tid / OUT_DIM, j = tid - q * OUT_DIM;
        double tot = 0.0;
#pragma unroll
        for (int wq = 0; wq < NW; ++wq) tot += part_s[wq][q];
        tot *= 0.34657359027997264;           // 1/c2 = ln2/2, applied once
        out[(b0 + q) * OUT_DIM + j] =
            (float)fma(tot, (double)W[j], (double)bvec[j]);
    }
}

extern "C" void kernel_launch(void* const* d_in, const int* in_sizes, int n_in,
                              void* d_out, int out_size, void* d_ws, size_t ws_size,
                              hipStream_t stream) {
    const float* x  = (const float*)d_in[0];   // (512, 784, 1)
    const float* C  = (const float*)d_in[1];   // (1, 1024)
    const float* W  = (const float*)d_in[2];   // (1, 10)
    const float* bv = (const float*)d_in[3];   // (10,)
    float* out      = (float*)d_out;           // (512, 10)
    hipLaunchKernelGGL(ssm_hippo_scan, dim3(256), dim3(512), 0, stream,
                       x, C, W, bv, out);
}